// Round 7
// baseline (239.900 us; speedup 1.0000x reference)
//
#include <hip/hip_runtime.h>
#include <hip/hip_bf16.h>
#include <math.h>

#define N 8192
#define D 1024
#define BM 256
#define BK 64
#define NTIL 32                         // 8192/256
#define NBLK 528                        // 32*33/2 lower-tri tiles
#define ITERS 8                         // 16 K-tiles / 2 per iteration

typedef __bf16 bf16_t;
typedef bf16_t bf16x4 __attribute__((ext_vector_type(4)));
typedef bf16_t bf16x8 __attribute__((ext_vector_type(8)));
typedef float f32x4 __attribute__((ext_vector_type(4)));

// ---------------------------------------------------------------------------
// Kernel 1: L2-normalize each row, cast to bf16. Wave-per-row (no LDS, no
// __syncthreads). Also zeroes sumExp/posSum (replaces the memset dispatch).
// ---------------------------------------------------------------------------
__global__ __launch_bounds__(256) void norm_cast(const float* __restrict__ in,
                                                 bf16_t* __restrict__ out,
                                                 float* __restrict__ sumExp,
                                                 float* __restrict__ posSum) {
    const int wave = threadIdx.x >> 6, lane = threadIdx.x & 63;
    const int row  = blockIdx.x * 4 + wave;
    const float4* src = (const float4*)(in + (size_t)row * D);
    float4 v[4];
    float ss = 0.f;
    #pragma unroll
    for (int i = 0; i < 4; ++i) {
        v[i] = src[lane + 64 * i];
        ss += v[i].x * v[i].x + v[i].y * v[i].y + v[i].z * v[i].z + v[i].w * v[i].w;
    }
    #pragma unroll
    for (int off = 32; off >= 1; off >>= 1) ss += __shfl_xor(ss, off, 64);
    const float scale = 1.0f / fmaxf(sqrtf(ss), 1e-12f);
    bf16x4* dst = (bf16x4*)(out + (size_t)row * D);
    #pragma unroll
    for (int i = 0; i < 4; ++i) {
        bf16x4 o;
        o[0] = (bf16_t)(v[i].x * scale);
        o[1] = (bf16_t)(v[i].y * scale);
        o[2] = (bf16_t)(v[i].z * scale);
        o[3] = (bf16_t)(v[i].w * scale);
        dst[lane + 64 * i] = o;
    }
    if (lane == 0) { sumExp[row] = 0.f; posSum[row] = 0.f; }
}

// ---------------------------------------------------------------------------
// Kernel 2: fused symmetric  C = E·E^T / T -> exp -> masked row+col sums.
// 256x256 tiles, BK=64, 8 waves (2M x 4N), 8-phase schedule (2 K-tiles/iter),
// counted vmcnt(4) at phases 4/8, double-buffered LDS = exactly 128 KiB.
// R7 = resubmitted R6 EXPERIMENT (m198 replica): NO swizzle anywhere.
// Staging source is fully LINEAR (each 8-lane group reads one dense 128B row
// chunk -> max request merging), LDS layout linear, frag reads linear (16-way
// bank conflicts, accepted: m198 proved this structure reaches 46% with them).
// Decisive A/B for the "cross-64B per-lane source permutation defeats the
// global_load_lds request merger" theory.
// ---------------------------------------------------------------------------
__global__ __launch_bounds__(512, 2) void gemm_fused(const bf16_t* __restrict__ E,
                                                     const int* __restrict__ labels,
                                                     float* __restrict__ sumExp,
                                                     float* __restrict__ posSum) {
    __shared__ bf16_t As[2][2][128 * 64];   // [buf][half(rows 0-127 / 128-255)][...]
    __shared__ bf16_t Bs[2][2][128 * 64];   // [buf][half(cols 0-127 / 128-255)][...]
    // total static LDS: 131072 B

    // XCD-aware bijective swizzle (528 % 8 == 0)
    const int b0 = blockIdx.x;
    const int b  = (b0 & 7) * (NBLK / 8) + (b0 >> 3);

    // triangular decode: b -> (ti >= tj)
    int ti = (int)((sqrtf(8.0f * (float)b + 1.0f) - 1.0f) * 0.5f);
    while ((ti + 1) * (ti + 2) / 2 <= b) ++ti;
    while (ti * (ti + 1) / 2 > b) --ti;
    const int tj = b - ti * (ti + 1) / 2;
    const bool isDiag = (ti == tj);

    const int tid  = threadIdx.x;
    const int wave = tid >> 6;
    const int lane = tid & 63;
    const int lr   = lane & 15;
    const int q    = lane >> 4;
    const int wm   = wave >> 2;     // 0..1 : row half
    const int wn   = wave & 3;      // 0..3 : 64-col strip
    const int rowStart = ti * BM;
    const int colStart = tj * BM;

    f32x4 acc[8][4];
    #pragma unroll
    for (int m = 0; m < 8; ++m)
        #pragma unroll
        for (int n = 0; n < 4; ++n) acc[m][n] = {0.f, 0.f, 0.f, 0.f};

    // ---- staging geometry: thread covers linear 16B units of a 128x64
    // half-tile. LINEAR: lane group of 8 reads one dense 128B row chunk.
    const int r0  = tid >> 3;                    // 0..63 (second load adds 64 rows)
    const int lu0 = tid & 7;                     // linear unit in row
    const char* gA = (const char*)(E + (size_t)rowStart * D) + (size_t)r0 * (D * 2) + lu0 * 16;
    const char* gB = (const char*)(E + (size_t)colStart * D) + (size_t)r0 * (D * 2) + lu0 * 16;

    #define STAGE_A(buf, h, kb) do {                                                     \
        const char* g0_ = gA + (size_t)(h) * (128 * 2048) + (kb);                        \
        char* l0_ = (char*)&As[buf][h][0] + wave * 1024;                                 \
        __builtin_amdgcn_global_load_lds((const __attribute__((address_space(1))) void*)g0_, \
            (__attribute__((address_space(3))) void*)l0_, 16, 0, 0);                     \
        __builtin_amdgcn_global_load_lds(                                                \
            (const __attribute__((address_space(1))) void*)(g0_ + 64 * 2048),            \
            (__attribute__((address_space(3))) void*)(l0_ + 8192), 16, 0, 0);            \
    } while (0)
    #define STAGE_B(buf, h, kb) do {                                                     \
        const char* g0_ = gB + (size_t)(h) * (128 * 2048) + (kb);                        \
        char* l0_ = (char*)&Bs[buf][h][0] + wave * 1024;                                 \
        __builtin_amdgcn_global_load_lds((const __attribute__((address_space(1))) void*)g0_, \
            (__attribute__((address_space(3))) void*)l0_, 16, 0, 0);                     \
        __builtin_amdgcn_global_load_lds(                                                \
            (const __attribute__((address_space(1))) void*)(g0_ + 64 * 2048),            \
            (__attribute__((address_space(3))) void*)(l0_ + 8192), 16, 0, 0);            \
    } while (0)

    // ---- frag-read offsets, LINEAR: unit = k*4 + q.
    const int su0 = (0 + q) * 16;     // k = 0
    const int su1 = (4 + q) * 16;     // k = 1
    const char* rA0 = (const char*)&As[0][wm][0] + lr * 128;
    const char* rA1 = (const char*)&As[1][wm][0] + lr * 128;
    const char* rB0 = (const char*)&Bs[0][wn >> 1][0] + (wn & 1) * 8192 + lr * 128;
    const char* rB1 = (const char*)&Bs[1][wn >> 1][0] + (wn & 1) * 8192 + lr * 128;

    #define LD_A4(DST, RBASE, MOFFB, SU) do {                                            \
        _Pragma("unroll")                                                                \
        for (int m_ = 0; m_ < 4; ++m_)                                                   \
            DST[m_] = *(const bf16x8*)((RBASE) + (MOFFB) + m_ * 2048 + (SU));            \
    } while (0)
    #define LD_B4(DST, RBASE, SU) do {                                                   \
        _Pragma("unroll")                                                                \
        for (int n_ = 0; n_ < 4; ++n_)                                                   \
            DST[n_] = *(const bf16x8*)((RBASE) + n_ * 2048 + (SU));                      \
    } while (0)
    #define MFMA_QUAD(AF, BF, MO) do {                                                   \
        _Pragma("unroll")                                                                \
        for (int m_ = 0; m_ < 4; ++m_) {                                                 \
            _Pragma("unroll")                                                            \
            for (int n_ = 0; n_ < 4; ++n_)                                               \
                acc[(MO) + m_][n_] = __builtin_amdgcn_mfma_f32_16x16x32_bf16(            \
                    AF[m_], BF[n_], acc[(MO) + m_][n_], 0, 0, 0);                        \
        }                                                                                \
    } while (0)
    #define PHASE_MID() do {                                                             \
        __builtin_amdgcn_s_barrier();                                                    \
        asm volatile("s_waitcnt lgkmcnt(0)");                                            \
        __builtin_amdgcn_sched_barrier(0);                                               \
        __builtin_amdgcn_s_setprio(1);                                                   \
    } while (0)
    #define PHASE_END() do {                                                             \
        __builtin_amdgcn_s_setprio(0);                                                   \
        __builtin_amdgcn_s_barrier();                                                    \
    } while (0)

    bf16x8 a0[4], a1[4], bq0[4], bq1[4];

    // ---- prologue: buf0 (K-tile 0) fully + buf1.B (K-tile 1). 12 loads;
    // vmcnt(4) -> buf0's 8 landed, buf1.B's 4 stay in flight.
    STAGE_B(0, 0, 0);  STAGE_B(0, 1, 0);
    STAGE_A(0, 0, 0);  STAGE_A(0, 1, 0);
    STAGE_B(1, 0, 128); STAGE_B(1, 1, 128);
    asm volatile("s_waitcnt vmcnt(4)" ::: "memory");
    __builtin_amdgcn_sched_barrier(0);
    __builtin_amdgcn_s_barrier();

    #pragma unroll 1
    for (int it = 0; it < ITERS; ++it) {
        const bool lastIt = (it == ITERS - 1);
        const int kb1 = (2 * it + 1) * 128;   // buf1's K-tile (byte col offset)
        const int kb2 = (2 * it + 2) * 128;   // next buf0 K-tile
        const int kb3 = (2 * it + 3) * 128;   // next buf1 K-tile

        // phase 1: buf0, m0-3, k0 | stage buf1.A h0 (this iter's second tile)
        LD_A4(a0, rA0, 0, su0);
        LD_B4(bq0, rB0, su0);
        STAGE_A(1, 0, kb1);
        PHASE_MID();
        MFMA_QUAD(a0, bq0, 0);
        PHASE_END();

        // phase 2: buf0, m0-3, k1 | stage buf1.A h1
        LD_A4(a1, rA0, 0, su1);
        LD_B4(bq1, rB0, su1);
        STAGE_A(1, 1, kb1);
        PHASE_MID();
        MFMA_QUAD(a1, bq1, 0);
        PHASE_END();

        // phase 3: buf0, m4-7, k0 | stage buf0.B h0 (K-tile 2it+2)
        LD_A4(a0, rA0, 8192, su0);
        if (!lastIt) STAGE_B(0, 0, kb2);
        PHASE_MID();
        MFMA_QUAD(a0, bq0, 4);
        PHASE_END();

        // phase 4: buf0, m4-7, k1 | stage buf0.B h1 | counted vmcnt:
        // waits the oldest 8 = buf1.A (ph1/2) + buf1.B (prev ph7/8 or prologue)
        LD_A4(a1, rA0, 8192, su1);
        if (!lastIt) {
            STAGE_B(0, 1, kb2);
            asm volatile("s_waitcnt vmcnt(4)" ::: "memory");
        } else {
            asm volatile("s_waitcnt vmcnt(0)" ::: "memory");
        }
        __builtin_amdgcn_sched_barrier(0);
        PHASE_MID();
        MFMA_QUAD(a1, bq1, 4);
        PHASE_END();

        // phase 5: buf1, m0-3, k0 | stage buf0.A h0
        LD_A4(a0, rA1, 0, su0);
        LD_B4(bq0, rB1, su0);
        if (!lastIt) STAGE_A(0, 0, kb2);
        PHASE_MID();
        MFMA_QUAD(a0, bq0, 0);
        PHASE_END();

        // phase 6: buf1, m0-3, k1 | stage buf0.A h1
        LD_A4(a1, rA1, 0, su1);
        LD_B4(bq1, rB1, su1);
        if (!lastIt) STAGE_A(0, 1, kb2);
        PHASE_MID();
        MFMA_QUAD(a1, bq1, 0);
        PHASE_END();

        // phase 7: buf1, m4-7, k0 | stage buf1.B h0 (K-tile 2it+3)
        LD_A4(a0, rA1, 8192, su0);
        if (!lastIt) STAGE_B(1, 0, kb3);
        PHASE_MID();
        MFMA_QUAD(a0, bq0, 4);
        PHASE_END();

        // phase 8: buf1, m4-7, k1 | stage buf1.B h1 | counted vmcnt:
        // waits the oldest 8 = buf0.B (ph3/4) + buf0.A (ph5/6)
        LD_A4(a1, rA1, 8192, su1);
        if (!lastIt) {
            STAGE_B(1, 1, kb3);
            asm volatile("s_waitcnt vmcnt(4)" ::: "memory");
            __builtin_amdgcn_sched_barrier(0);
        }
        PHASE_MID();
        MFMA_QUAD(a1, bq1, 4);
        PHASE_END();
    }

    // ---- epilogue: C/D layout col=lane&15, row=q*4+e (m89/m91).
    // Labels read straight from global (L2-resident, once per block).
    const float invT = 1.0f / 0.07f;
    int lc[4];
    #pragma unroll
    for (int n = 0; n < 4; ++n)
        lc[n] = labels[colStart + wn * 64 + n * 16 + lr];

    float colAll[4] = {0.f, 0.f, 0.f, 0.f};
    float colPos[4] = {0.f, 0.f, 0.f, 0.f};
    #pragma unroll
    for (int m = 0; m < 8; ++m) {
        #pragma unroll
        for (int e = 0; e < 4; ++e) {
            const int rloc = wm * 128 + m * 16 + q * 4 + e;
            const int gi   = rowStart + rloc;
            const int li   = labels[gi];
            float s_all = 0.f, s_pos = 0.f;
            #pragma unroll
            for (int n = 0; n < 4; ++n) {
                const int cloc = wn * 64 + n * 16 + lr;
                const int gj   = colStart + cloc;
                const float v  = __expf(acc[m][n][e] * invT);
                const bool same = (lc[n] == li);
                s_all += v;
                if (same && gi != gj) s_pos += v;
                if (!isDiag) {            // wave-uniform branch
                    colAll[n] += v;       // gi != gj guaranteed off-diagonal
                    if (same) colPos[n] += v;
                }
            }
            #pragma unroll
            for (int off = 1; off < 16; off <<= 1) {
                s_all += __shfl_xor(s_all, off, 64);
                s_pos += __shfl_xor(s_pos, off, 64);
            }
            if (lr == 0) {
                atomicAdd(&sumExp[gi], s_all);
                atomicAdd(&posSum[gi], s_pos);
            }
        }
    }
    if (!isDiag) {
        #pragma unroll
        for (int n = 0; n < 4; ++n) {
            float a = colAll[n], p = colPos[n];
            a += __shfl_xor(a, 16, 64);  a += __shfl_xor(a, 32, 64);
            p += __shfl_xor(p, 16, 64);  p += __shfl_xor(p, 32, 64);
            if (q == 0) {
                const int gj = colStart + wn * 64 + n * 16 + lr;
                atomicAdd(&sumExp[gj], a);
                atomicAdd(&posSum[gj], p);
            }
        }
    }
}

// ---------------------------------------------------------------------------
// Kernel 3: loss_i = log(sumExp_i / posSum_i); out = mean(loss).
// ---------------------------------------------------------------------------
__global__ __launch_bounds__(1024) void finalize(const float* __restrict__ sumExp,
                                                 const float* __restrict__ posSum,
                                                 float* __restrict__ out) {
    const int tid = threadIdx.x;
    float s = 0.f;
    #pragma unroll
    for (int i = tid; i < N; i += 1024)
        s += __logf(sumExp[i] / posSum[i]);
    #pragma unroll
    for (int off = 32; off >= 1; off >>= 1) s += __shfl_xor(s, off, 64);
    __shared__ float red[16];
    if ((tid & 63) == 0) red[tid >> 6] = s;
    __syncthreads();
    if (tid == 0) {
        float t = 0.f;
        #pragma unroll
        for (int i = 0; i < 16; ++i) t += red[i];
        out[0] = t / (float)N;
    }
}

extern "C" void kernel_launch(void* const* d_in, const int* in_sizes, int n_in,
                              void* d_out, int out_size, void* d_ws, size_t ws_size,
                              hipStream_t stream) {
    const float* emb    = (const float*)d_in[0];
    const int*   labels = (const int*)d_in[1];
    float* out = (float*)d_out;

    // ws layout: [sumExp: N floats][posSum: N floats][EN: N*D bf16]
    float*  sumExp = (float*)d_ws;
    float*  posSum = sumExp + N;
    bf16_t* EN     = (bf16_t*)((char*)d_ws + (size_t)2 * N * sizeof(float));

    norm_cast<<<N / 4, 256, 0, stream>>>(emb, EN, sumExp, posSum);

    gemm_fused<<<NBLK, 512, 0, stream>>>(EN, labels, sumExp, posSum);

    finalize<<<1, 1024, 0, stream>>>(sumExp, posSum, out);
}

// Round 8
// 230.338 us; speedup vs baseline: 1.0415x; 1.0415x over previous
//
#include <hip/hip_runtime.h>
#include <hip/hip_bf16.h>
#include <math.h>

#define N 8192
#define D 1024
#define BM 256
#define BN 128
#define BK 32
#define NBLK 1056                       // sum_{ti=0}^{31} (2*ti+2) half-tiles
#define KSTEPS 32                       // 1024/32

typedef __bf16 bf16_t;
typedef bf16_t bf16x4 __attribute__((ext_vector_type(4)));
typedef bf16_t bf16x8 __attribute__((ext_vector_type(8)));
typedef float f32x4 __attribute__((ext_vector_type(4)));

// ---------------------------------------------------------------------------
// Kernel 1: L2-normalize each row, cast to bf16. Wave-per-row. Also zeroes
// sumExp/posSum (replaces the memset dispatch).
// ---------------------------------------------------------------------------
__global__ __launch_bounds__(256) void norm_cast(const float* __restrict__ in,
                                                 bf16_t* __restrict__ out,
                                                 float* __restrict__ sumExp,
                                                 float* __restrict__ posSum) {
    const int wave = threadIdx.x >> 6, lane = threadIdx.x & 63;
    const int row  = blockIdx.x * 4 + wave;
    const float4* src = (const float4*)(in + (size_t)row * D);
    float4 v[4];
    float ss = 0.f;
    #pragma unroll
    for (int i = 0; i < 4; ++i) {
        v[i] = src[lane + 64 * i];
        ss += v[i].x * v[i].x + v[i].y * v[i].y + v[i].z * v[i].z + v[i].w * v[i].w;
    }
    #pragma unroll
    for (int off = 32; off >= 1; off >>= 1) ss += __shfl_xor(ss, off, 64);
    const float scale = 1.0f / fmaxf(sqrtf(ss), 1e-12f);
    bf16x4* dst = (bf16x4*)(out + (size_t)row * D);
    #pragma unroll
    for (int i = 0; i < 4; ++i) {
        bf16x4 o;
        o[0] = (bf16_t)(v[i].x * scale);
        o[1] = (bf16_t)(v[i].y * scale);
        o[2] = (bf16_t)(v[i].z * scale);
        o[3] = (bf16_t)(v[i].w * scale);
        dst[lane + 64 * i] = o;
    }
    if (lane == 0) { sumExp[row] = 0.f; posSum[row] = 0.f; }
}

// ---------------------------------------------------------------------------
// Kernel 2: fused symmetric  C = E·E^T / T -> exp -> masked row+col sums.
// R8: 256x128 blocks (each former 256^2 tile split into 2 col-halves).
// 8 waves (2 row-halves x 4 col-strips), wave output 128x32 -> acc = 64 regs
// -> launch_bounds(512,4) -> 4 waves/SIMD -> TWO blocks co-resident per CU
// (LDS 72 KB x 2 = 144 <= 160). Triple-buffered BK=32 ring, one counted
// vmcnt(3) per K-step (1 K-tile of prefetch slack), 2 phases/K-step.
// LDS swizzle: phys 16B unit = logical ^ ((row>>1)&3) (the R0-proven
// conflict-free pattern for 64B rows); staging keeps LDS dest linear and
// inverse-permutes the GLOBAL source (rule 21: same involution both sides).
// ---------------------------------------------------------------------------
__global__ __launch_bounds__(512, 4) void gemm_fused(const bf16_t* __restrict__ E,
                                                     const int* __restrict__ labels,
                                                     float* __restrict__ sumExp,
                                                     float* __restrict__ posSum) {
    __shared__ bf16_t As[3][256 * 32];   // 3 x 16 KB ring
    __shared__ bf16_t Bs[3][128 * 32];   // 3 x  8 KB ring   (total 72 KB)

    // XCD-aware bijective swizzle (1056 % 8 == 0)
    const int b0 = blockIdx.x;
    const int b  = (b0 & 7) * (NBLK / 8) + (b0 >> 3);

    // decode: b -> (ti, tj2), tj2 in [0, 2*ti+2). cum(ti) = ti*(ti+1).
    int ti = (int)((sqrtf(4.0f * (float)b + 1.0f) - 1.0f) * 0.5f);
    while ((ti + 1) * (ti + 2) <= b) ++ti;
    while (ti * (ti + 1) > b) --ti;
    const int tj2 = b - ti * (ti + 1);
    const bool isDiag = ((tj2 >> 1) == ti);   // col-half of a diagonal 256-tile

    const int tid  = threadIdx.x;
    const int wave = tid >> 6;
    const int lane = tid & 63;
    const int lr   = lane & 15;
    const int q    = lane >> 4;
    const int wm   = wave >> 2;     // 0..1 : 128-row half
    const int wn   = wave & 3;      // 0..3 : 32-col strip
    const int rowStart = ti * BM;
    const int colStart = tj2 * BN;

    f32x4 acc[8][2];
    #pragma unroll
    for (int m = 0; m < 8; ++m) {
        acc[m][0] = {0.f, 0.f, 0.f, 0.f};
        acc[m][1] = {0.f, 0.f, 0.f, 0.f};
    }

    // ---- staging geometry: 512 threads x 16B = 8 KB = 128 rows x 4 units.
    // phys unit u=tid -> row r=tid>>2, unit j=tid&2..; logical unit
    // j ^ ((r>>1)&3) (inverse-swizzled global source, linear LDS dest).
    const int r0  = tid >> 2;                    // 0..127
    const int lu0 = (tid & 3) ^ ((r0 >> 1) & 3);
    const char* gA = (const char*)(E + (size_t)rowStart * D) + (size_t)r0 * (D * 2) + lu0 * 16;
    const char* gB = (const char*)(E + (size_t)colStart * D) + (size_t)r0 * (D * 2) + lu0 * 16;

    // stage K-tile T into ring slot BI: A rows 0-127, A rows 128-255, B (3 gloads)
    #define STAGE_T(T, BI) do {                                                          \
        const char* ga_ = gA + (size_t)(T) * 64;                                         \
        const char* gb_ = gB + (size_t)(T) * 64;                                         \
        char* la_ = (char*)&As[BI][0] + wave * 1024;                                     \
        char* lb_ = (char*)&Bs[BI][0] + wave * 1024;                                     \
        __builtin_amdgcn_global_load_lds((const __attribute__((address_space(1))) void*)ga_, \
            (__attribute__((address_space(3))) void*)la_, 16, 0, 0);                     \
        __builtin_amdgcn_global_load_lds(                                                \
            (const __attribute__((address_space(1))) void*)(ga_ + 128 * 2048),           \
            (__attribute__((address_space(3))) void*)(la_ + 8192), 16, 0, 0);            \
        __builtin_amdgcn_global_load_lds((const __attribute__((address_space(1))) void*)gb_, \
            (__attribute__((address_space(3))) void*)lb_, 16, 0, 0);                     \
    } while (0)

    // ---- frag reads. 64B rows (BK=32). A row = wm*128 + m*16 + lr;
    // B row = wn*32 + n*16 + lr. Unit q, phys = q ^ ((lr>>1)&3) (row offsets
    // are multiples of 16 rows -> XOR term depends only on lr).
    const int su = (q ^ ((lr >> 1) & 3)) * 16;

    #define MFMA8(MO) do {                                                               \
        _Pragma("unroll")                                                                \
        for (int m_ = 0; m_ < 4; ++m_) {                                                 \
            _Pragma("unroll")                                                            \
            for (int n_ = 0; n_ < 2; ++n_)                                               \
                acc[(MO) + m_][n_] = __builtin_amdgcn_mfma_f32_16x16x32_bf16(            \
                    af[m_], bfr[n_], acc[(MO) + m_][n_], 0, 0, 0);                       \
        }                                                                                \
    } while (0)
    #define PHASE_MID() do {                                                             \
        __builtin_amdgcn_s_barrier();                                                    \
        asm volatile("s_waitcnt lgkmcnt(0)");                                            \
        __builtin_amdgcn_sched_barrier(0);                                               \
        __builtin_amdgcn_s_setprio(1);                                                   \
    } while (0)
    #define PHASE_END() do {                                                             \
        __builtin_amdgcn_s_setprio(0);                                                   \
        __builtin_amdgcn_s_barrier();                                                    \
    } while (0)

    // One K-step: ph1 {read A m0-3 + B n0-1 | stage T+2 -> BI2 | MFMA m0-3}
    //             ph2 {read A m4-7 | counted vmcnt | MFMA m4-7}
    #define STEP(T, BI, BI2, DOSTAGE, VMASM) do {                                        \
        const char* aB_ = (const char*)&As[BI][0] + (wm * 128 + lr) * 64 + su;           \
        const char* bB_ = (const char*)&Bs[BI][0] + (wn * 32 + lr) * 64 + su;            \
        _Pragma("unroll")                                                                \
        for (int m_ = 0; m_ < 4; ++m_)                                                   \
            af[m_] = *(const bf16x8*)(aB_ + m_ * 1024);                                  \
        bfr[0] = *(const bf16x8*)(bB_);                                                  \
        bfr[1] = *(const bf16x8*)(bB_ + 1024);                                           \
        if (DOSTAGE) STAGE_T((T) + 2, BI2);                                              \
        PHASE_MID();                                                                     \
        MFMA8(0);                                                                        \
        PHASE_END();                                                                     \
        _Pragma("unroll")                                                                \
        for (int m_ = 0; m_ < 4; ++m_)                                                   \
            af[m_] = *(const bf16x8*)(aB_ + (4 + m_) * 1024);                            \
        asm volatile(VMASM ::: "memory");                                                \
        __builtin_amdgcn_sched_barrier(0);                                               \
        PHASE_MID();                                                                     \
        MFMA8(4);                                                                        \
        PHASE_END();                                                                     \
    } while (0)

    bf16x8 af[4], bfr[2];

    // ---- prologue: stage K-tiles 0,1 (6 gloads); vmcnt(3) drains tile 0.
    STAGE_T(0, 0);
    STAGE_T(1, 1);
    asm volatile("s_waitcnt vmcnt(3)" ::: "memory");
    __builtin_amdgcn_sched_barrier(0);
    __builtin_amdgcn_s_barrier();

    // main loop: t = 0..29 stage t+2, counted vmcnt(3); tail t = 30,31 drain.
    #pragma unroll 1
    for (int tt = 0; tt < 30; tt += 3) {
        STEP(tt,     0, 2, true, "s_waitcnt vmcnt(3)");
        STEP(tt + 1, 1, 0, true, "s_waitcnt vmcnt(3)");
        STEP(tt + 2, 2, 1, true, "s_waitcnt vmcnt(3)");
    }
    STEP(30, 0, 2, false, "s_waitcnt vmcnt(0)");
    STEP(31, 1, 0, false, "s_waitcnt vmcnt(0)");

    // ---- epilogue: C/D layout col=lane&15, row=q*4+e (m89/m91).
    // Labels read straight from global (L2-resident, once per block).
    const float invT = 1.0f / 0.07f;
    int lc[2];
    lc[0] = labels[colStart + wn * 32 + lr];
    lc[1] = labels[colStart + wn * 32 + 16 + lr];

    float colAll[2] = {0.f, 0.f};
    float colPos[2] = {0.f, 0.f};
    #pragma unroll
    for (int m = 0; m < 8; ++m) {
        #pragma unroll
        for (int e = 0; e < 4; ++e) {
            const int rloc = wm * 128 + m * 16 + q * 4 + e;
            const int gi   = rowStart + rloc;
            const int li   = labels[gi];
            float s_all = 0.f, s_pos = 0.f;
            #pragma unroll
            for (int n = 0; n < 2; ++n) {
                const int cloc = wn * 32 + n * 16 + lr;
                const int gj   = colStart + cloc;
                const float v  = __expf(acc[m][n][e] * invT);
                const bool same = (lc[n] == li);
                s_all += v;
                if (same && gi != gj) s_pos += v;
                if (!isDiag) {            // wave-uniform branch
                    colAll[n] += v;       // gi != gj guaranteed off-diagonal
                    if (same) colPos[n] += v;
                }
            }
            #pragma unroll
            for (int off = 1; off < 16; off <<= 1) {
                s_all += __shfl_xor(s_all, off, 64);
                s_pos += __shfl_xor(s_pos, off, 64);
            }
            if (lr == 0) {
                atomicAdd(&sumExp[gi], s_all);
                atomicAdd(&posSum[gi], s_pos);
            }
        }
    }
    if (!isDiag) {
        #pragma unroll
        for (int n = 0; n < 2; ++n) {
            float a = colAll[n], p = colPos[n];
            a += __shfl_xor(a, 16, 64);  a += __shfl_xor(a, 32, 64);
            p += __shfl_xor(p, 16, 64);  p += __shfl_xor(p, 32, 64);
            if (q == 0) {
                const int gj = colStart + wn * 32 + n * 16 + lr;
                atomicAdd(&sumExp[gj], a);
                atomicAdd(&posSum[gj], p);
            }
        }
    }
}

// ---------------------------------------------------------------------------
// Kernel 3: loss_i = log(sumExp_i / posSum_i); out = mean(loss).
// ---------------------------------------------------------------------------
__global__ __launch_bounds__(1024) void finalize(const float* __restrict__ sumExp,
                                                 const float* __restrict__ posSum,
                                                 float* __restrict__ out) {
    const int tid = threadIdx.x;
    float s = 0.f;
    #pragma unroll
    for (int i = tid; i < N; i += 1024)
        s += __logf(sumExp[i] / posSum[i]);
    #pragma unroll
    for (int off = 32; off >= 1; off >>= 1) s += __shfl_xor(s, off, 64);
    __shared__ float red[16];
    if ((tid & 63) == 0) red[tid >> 6] = s;
    __syncthreads();
    if (tid == 0) {
        float t = 0.f;
        #pragma unroll
        for (int i = 0; i < 16; ++i) t += red[i];
        out[0] = t / (float)N;
    }
}

extern "C" void kernel_launch(void* const* d_in, const int* in_sizes, int n_in,
                              void* d_out, int out_size, void* d_ws, size_t ws_size,
                              hipStream_t stream) {
    const float* emb    = (const float*)d_in[0];
    const int*   labels = (const int*)d_in[1];
    float* out = (float*)d_out;

    // ws layout: [sumExp: N floats][posSum: N floats][EN: N*D bf16]
    float*  sumExp = (float*)d_ws;
    float*  posSum = sumExp + N;
    bf16_t* EN     = (bf16_t*)((char*)d_ws + (size_t)2 * N * sizeof(float));

    norm_cast<<<N / 4, 256, 0, stream>>>(emb, EN, sumExp, posSum);

    gemm_fused<<<NBLK, 512, 0, stream>>>(EN, labels, sumExp, posSum);

    finalize<<<1, 1024, 0, stream>>>(sumExp, posSum, out);
}

// Round 9
// 206.719 us; speedup vs baseline: 1.1605x; 1.1143x over previous
//
#include <hip/hip_runtime.h>
#include <hip/hip_bf16.h>
#include <math.h>

#define N 8192
#define D 1024
#define BM 256
#define BK 64
#define NQUART 64                       // 16 tiles (ti=31, tj=0..15) x 4 quadrants
#define NFULL 512                       // 528 - 16 quartered tiles
#define NBLK (NQUART + NFULL)           // 576
#define ITERS 8                         // full path: 16 K-tiles / 2 per iter

typedef __bf16 bf16_t;
typedef bf16_t bf16x4 __attribute__((ext_vector_type(4)));
typedef bf16_t bf16x8 __attribute__((ext_vector_type(8)));
typedef float f32x4 __attribute__((ext_vector_type(4)));

// ---------------------------------------------------------------------------
// Kernel 1: L2-normalize each row, cast to bf16. Wave-per-row. Also zeroes
// sumExp/posSum (replaces the memset dispatch).
// ---------------------------------------------------------------------------
__global__ __launch_bounds__(256) void norm_cast(const float* __restrict__ in,
                                                 bf16_t* __restrict__ out,
                                                 float* __restrict__ sumExp,
                                                 float* __restrict__ posSum) {
    const int wave = threadIdx.x >> 6, lane = threadIdx.x & 63;
    const int row  = blockIdx.x * 4 + wave;
    const float4* src = (const float4*)(in + (size_t)row * D);
    float4 v[4];
    float ss = 0.f;
    #pragma unroll
    for (int i = 0; i < 4; ++i) {
        v[i] = src[lane + 64 * i];
        ss += v[i].x * v[i].x + v[i].y * v[i].y + v[i].z * v[i].z + v[i].w * v[i].w;
    }
    #pragma unroll
    for (int off = 32; off >= 1; off >>= 1) ss += __shfl_xor(ss, off, 64);
    const float scale = 1.0f / fmaxf(sqrtf(ss), 1e-12f);
    bf16x4* dst = (bf16x4*)(out + (size_t)row * D);
    #pragma unroll
    for (int i = 0; i < 4; ++i) {
        bf16x4 o;
        o[0] = (bf16_t)(v[i].x * scale);
        o[1] = (bf16_t)(v[i].y * scale);
        o[2] = (bf16_t)(v[i].z * scale);
        o[3] = (bf16_t)(v[i].w * scale);
        dst[lane + 64 * i] = o;
    }
    if (lane == 0) { sumExp[row] = 0.f; posSum[row] = 0.f; }
}

// ---------------------------------------------------------------------------
// Kernel 2: fused symmetric  C = E·E^T / T -> exp -> masked row+col sums.
// R9 = R2's verified kernel (146 us, conflict-free) with MAKESPAN SURGERY:
//   - 16 strictly-off-diagonal tiles (ti=31, tj=0..15) are split into 64
//     128x128 quarter-blocks (full K -> exp/epilogue identical), dispatched
//     FIRST (bid 0..63). They fill the front of the schedule.
//   - remaining 512 tiles run the unchanged 256^2 8-phase path = exactly
//     2 dispatch rounds at 1 block/CU.
//   Makespan: 3X (528 blocks) -> ~2X + Xq.
// ---------------------------------------------------------------------------
__global__ __launch_bounds__(512, 2) void gemm_fused(const bf16_t* __restrict__ E,
                                                     const int* __restrict__ labels,
                                                     float* __restrict__ sumExp,
                                                     float* __restrict__ posSum) {
    __shared__ bf16_t As[2][2][128 * 64];   // [buf][half][...] = 64 KB
    __shared__ bf16_t Bs[2][2][128 * 64];   // 64 KB  (total 131072 B)

    const int tid  = threadIdx.x;
    const int wave = tid >> 6;
    const int lane = tid & 63;
    const int lr   = lane & 15;
    const int q    = lane >> 4;
    const float invT = 1.0f / 0.07f;

    // swizzled frag-read units (identical formula both paths; 128B LDS rows)
    const int su0 = ((0 + q) ^ (lane & 7)) * 16;     // k = 0
    const int su1 = ((4 + q) ^ (lane & 7)) * 16;     // k = 1

    #define PHASE_MID() do {                                                             \
        __builtin_amdgcn_s_barrier();                                                    \
        asm volatile("s_waitcnt lgkmcnt(0)");                                            \
        __builtin_amdgcn_sched_barrier(0);                                               \
        __builtin_amdgcn_s_setprio(1);                                                   \
    } while (0)
    #define PHASE_END() do {                                                             \
        __builtin_amdgcn_s_setprio(0);                                                   \
        __builtin_amdgcn_s_barrier();                                                    \
    } while (0)

    if (blockIdx.x < NQUART) {
        // ===================================================================
        // QUARTER PATH: 128x128 tile, full K, double-buffered BK=64.
        // All quarters strictly below the diagonal (rowStart >= 7936 >
        // colStart+127 <= 4095): no diag masking, col-sums always on.
        // ===================================================================
        const int qb = ((int)blockIdx.x & 7) * 8 + ((int)blockIdx.x >> 3);
        const int p  = qb >> 2, qd = qb & 3;
        const int rowStart = 31 * BM + (qd >> 1) * 128;
        const int colStart = p * BM + (qd & 1) * 128;
        const int wm2 = wave >> 2;      // 0..1 : 64-row half
        const int wn2 = wave & 3;       // 0..3 : 32-col strip

        f32x4 acc[4][2];
        #pragma unroll
        for (int m = 0; m < 4; ++m) { acc[m][0] = {0,0,0,0}; acc[m][1] = {0,0,0,0}; }

        // staging: 512 thr x 16B = 8KB = 64 rows x 128B; 2 gloads per 128-row
        // panel. Same swizzle as full path: lu = (tid&7)^(row&7).
        const int r0  = tid >> 3;                    // 0..63
        const int lu0 = (tid & 7) ^ (r0 & 7);
        const char* gA = (const char*)(E + (size_t)rowStart * D) + (size_t)r0 * (D * 2) + lu0 * 16;
        const char* gB = (const char*)(E + (size_t)colStart * D) + (size_t)r0 * (D * 2) + lu0 * 16;

        #define QSTAGE(buf, kb) do {                                                     \
            const char* ga_ = gA + (kb);                                                 \
            const char* gb_ = gB + (kb);                                                 \
            char* la_ = (char*)&As[buf][0][0] + wave * 1024;                             \
            char* lb_ = (char*)&Bs[buf][0][0] + wave * 1024;                             \
            __builtin_amdgcn_global_load_lds((const __attribute__((address_space(1))) void*)ga_, \
                (__attribute__((address_space(3))) void*)la_, 16, 0, 0);                 \
            __builtin_amdgcn_global_load_lds(                                            \
                (const __attribute__((address_space(1))) void*)(ga_ + 64 * 2048),        \
                (__attribute__((address_space(3))) void*)(la_ + 8192), 16, 0, 0);        \
            __builtin_amdgcn_global_load_lds((const __attribute__((address_space(1))) void*)gb_, \
                (__attribute__((address_space(3))) void*)lb_, 16, 0, 0);                 \
            __builtin_amdgcn_global_load_lds(                                            \
                (const __attribute__((address_space(1))) void*)(gb_ + 64 * 2048),        \
                (__attribute__((address_space(3))) void*)(lb_ + 8192), 16, 0, 0);        \
        } while (0)

        bf16x8 qa[4], qbf[2];
        #define QLD(SU, BUF) do {                                                        \
            const char* aB_ = (const char*)&As[BUF][0][0] + (wm2 * 64 + lr) * 128 + (SU);\
            const char* bB_ = (const char*)&Bs[BUF][0][0] + (wn2 * 32 + lr) * 128 + (SU);\
            _Pragma("unroll")                                                            \
            for (int m_ = 0; m_ < 4; ++m_)                                               \
                qa[m_] = *(const bf16x8*)(aB_ + m_ * 2048);                              \
            qbf[0] = *(const bf16x8*)(bB_);                                              \
            qbf[1] = *(const bf16x8*)(bB_ + 2048);                                       \
        } while (0)
        #define QMFMA() do {                                                             \
            _Pragma("unroll")                                                            \
            for (int m_ = 0; m_ < 4; ++m_) {                                             \
                _Pragma("unroll")                                                        \
                for (int n_ = 0; n_ < 2; ++n_)                                           \
                    acc[m_][n_] = __builtin_amdgcn_mfma_f32_16x16x32_bf16(               \
                        qa[m_], qbf[n_], acc[m_][n_], 0, 0, 0);                          \
            }                                                                            \
        } while (0)

        QSTAGE(0, 0);
        asm volatile("s_waitcnt vmcnt(0)" ::: "memory");
        __builtin_amdgcn_sched_barrier(0);
        __builtin_amdgcn_s_barrier();

        #pragma unroll 1
        for (int it = 0; it < 16; ++it) {
            const int buf = it & 1;
            // ph1: k0 frags | stage next tile (4 gloads)
            QLD(su0, buf);
            if (it < 15) QSTAGE(buf ^ 1, (it + 1) * 128);
            PHASE_MID();
            QMFMA();
            PHASE_END();
            // ph2: k1 frags | drain next-tile stages (1 phase of cover)
            QLD(su1, buf);
            asm volatile("s_waitcnt vmcnt(0)" ::: "memory");
            __builtin_amdgcn_sched_barrier(0);
            PHASE_MID();
            QMFMA();
            PHASE_END();
        }

        // epilogue (always off-diagonal, gi != gj guaranteed)
        int lc[2];
        lc[0] = labels[colStart + wn2 * 32 + lr];
        lc[1] = labels[colStart + wn2 * 32 + 16 + lr];
        float colAll[2] = {0.f, 0.f}, colPos[2] = {0.f, 0.f};
        #pragma unroll
        for (int m = 0; m < 4; ++m) {
            #pragma unroll
            for (int e = 0; e < 4; ++e) {
                const int gi = rowStart + wm2 * 64 + m * 16 + q * 4 + e;
                const int li = labels[gi];
                float s_all = 0.f, s_pos = 0.f;
                #pragma unroll
                for (int n = 0; n < 2; ++n) {
                    const float v = __expf(acc[m][n][e] * invT);
                    const bool same = (lc[n] == li);
                    s_all += v;
                    if (same) s_pos += v;
                    colAll[n] += v;
                    if (same) colPos[n] += v;
                }
                #pragma unroll
                for (int off = 1; off < 16; off <<= 1) {
                    s_all += __shfl_xor(s_all, off, 64);
                    s_pos += __shfl_xor(s_pos, off, 64);
                }
                if (lr == 0) {
                    atomicAdd(&sumExp[gi], s_all);
                    atomicAdd(&posSum[gi], s_pos);
                }
            }
        }
        #pragma unroll
        for (int n = 0; n < 2; ++n) {
            float a = colAll[n], pp = colPos[n];
            a += __shfl_xor(a, 16, 64);  a += __shfl_xor(a, 32, 64);
            pp += __shfl_xor(pp, 16, 64); pp += __shfl_xor(pp, 32, 64);
            if (q == 0) {
                const int gj = colStart + wn2 * 32 + n * 16 + lr;
                atomicAdd(&sumExp[gj], a);
                atomicAdd(&posSum[gj], pp);
            }
        }
        return;
    }

    // =======================================================================
    // FULL PATH: R2's verified 256^2 / BK=64 / 8-phase kernel, unchanged
    // except the tile-index remap skipping the 16 quartered tiles.
    // =======================================================================
    const int f0 = (int)blockIdx.x - NQUART;
    const int f  = (f0 & 7) * (NFULL / 8) + (f0 >> 3);     // XCD swizzle, 512%8==0
    const int b  = (f < 496) ? f : f + 16;                 // skip tiles 496..511

    int ti = (int)((sqrtf(8.0f * (float)b + 1.0f) - 1.0f) * 0.5f);
    while ((ti + 1) * (ti + 2) / 2 <= b) ++ti;
    while (ti * (ti + 1) / 2 > b) --ti;
    const int tj = b - ti * (ti + 1) / 2;
    const bool isDiag = (ti == tj);

    const int wm   = wave >> 2;     // 0..1 : row half
    const int wn   = wave & 3;      // 0..3 : 64-col strip
    const int rowStart = ti * BM;
    const int colStart = tj * BM;

    f32x4 acc[8][4];
    #pragma unroll
    for (int m = 0; m < 8; ++m)
        #pragma unroll
        for (int n = 0; n < 4; ++n) acc[m][n] = {0.f, 0.f, 0.f, 0.f};

    const int r0  = tid >> 3;                    // 0..63 (second load adds 64 rows)
    const int lu0 = (tid & 7) ^ (r0 & 7);
    const char* gA = (const char*)(E + (size_t)rowStart * D) + (size_t)r0 * (D * 2) + lu0 * 16;
    const char* gB = (const char*)(E + (size_t)colStart * D) + (size_t)r0 * (D * 2) + lu0 * 16;

    #define STAGE_A(buf, h, kb) do {                                                     \
        const char* g0_ = gA + (size_t)(h) * (128 * 2048) + (kb);                        \
        char* l0_ = (char*)&As[buf][h][0] + wave * 1024;                                 \
        __builtin_amdgcn_global_load_lds((const __attribute__((address_space(1))) void*)g0_, \
            (__attribute__((address_space(3))) void*)l0_, 16, 0, 0);                     \
        __builtin_amdgcn_global_load_lds(                                                \
            (const __attribute__((address_space(1))) void*)(g0_ + 64 * 2048),            \
            (__attribute__((address_space(3))) void*)(l0_ + 8192), 16, 0, 0);            \
    } while (0)
    #define STAGE_B(buf, h, kb) do {                                                     \
        const char* g0_ = gB + (size_t)(h) * (128 * 2048) + (kb);                        \
        char* l0_ = (char*)&Bs[buf][h][0] + wave * 1024;                                 \
        __builtin_amdgcn_global_load_lds((const __attribute__((address_space(1))) void*)g0_, \
            (__attribute__((address_space(3))) void*)l0_, 16, 0, 0);                     \
        __builtin_amdgcn_global_load_lds(                                                \
            (const __attribute__((address_space(1))) void*)(g0_ + 64 * 2048),            \
            (__attribute__((address_space(3))) void*)(l0_ + 8192), 16, 0, 0);            \
    } while (0)

    const char* rA0 = (const char*)&As[0][wm][0] + lr * 128;
    const char* rA1 = (const char*)&As[1][wm][0] + lr * 128;
    const char* rB0 = (const char*)&Bs[0][wn >> 1][0] + (wn & 1) * 8192 + lr * 128;
    const char* rB1 = (const char*)&Bs[1][wn >> 1][0] + (wn & 1) * 8192 + lr * 128;

    #define LD_A4(DST, RBASE, MOFFB, SU) do {                                            \
        _Pragma("unroll")                                                                \
        for (int m_ = 0; m_ < 4; ++m_)                                                   \
            DST[m_] = *(const bf16x8*)((RBASE) + (MOFFB) + m_ * 2048 + (SU));            \
    } while (0)
    #define LD_B4(DST, RBASE, SU) do {                                                   \
        _Pragma("unroll")                                                                \
        for (int n_ = 0; n_ < 4; ++n_)                                                   \
            DST[n_] = *(const bf16x8*)((RBASE) + n_ * 2048 + (SU));                      \
    } while (0)
    #define MFMA_QUAD(AF, BF, MO) do {                                                   \
        _Pragma("unroll")                                                                \
        for (int m_ = 0; m_ < 4; ++m_) {                                                 \
            _Pragma("unroll")                                                            \
            for (int n_ = 0; n_ < 4; ++n_)                                               \
                acc[(MO) + m_][n_] = __builtin_amdgcn_mfma_f32_16x16x32_bf16(            \
                    AF[m_], BF[n_], acc[(MO) + m_][n_], 0, 0, 0);                        \
        }                                                                                \
    } while (0)

    bf16x8 a0[4], a1[4], bq0[4], bq1[4];

    STAGE_B(0, 0, 0);  STAGE_B(0, 1, 0);
    STAGE_A(0, 0, 0);  STAGE_A(0, 1, 0);
    STAGE_B(1, 0, 128); STAGE_B(1, 1, 128);
    asm volatile("s_waitcnt vmcnt(4)" ::: "memory");
    __builtin_amdgcn_sched_barrier(0);
    __builtin_amdgcn_s_barrier();

    #pragma unroll 1
    for (int it = 0; it < ITERS; ++it) {
        const bool lastIt = (it == ITERS - 1);
        const int kb1 = (2 * it + 1) * 128;
        const int kb2 = (2 * it + 2) * 128;
        const int kb3 = (2 * it + 3) * 128;

        LD_A4(a0, rA0, 0, su0);
        LD_B4(bq0, rB0, su0);
        STAGE_A(1, 0, kb1);
        PHASE_MID();
        MFMA_QUAD(a0, bq0, 0);
        PHASE_END();

        LD_A4(a1, rA0, 0, su1);
        LD_B4(bq1, rB0, su1);
        STAGE_A(1, 1, kb1);
        PHASE_MID();
        MFMA_QUAD(a1, bq1, 0);
        PHASE_END();

        LD_A4(a0, rA0, 8192, su0);
        if (!lastIt) STAGE_B(0, 0, kb2);
        PHASE_MID();
        MFMA_QUAD(a0, bq0, 4);
        PHASE_END();

        LD_A4(a1, rA0, 8192, su1);
        if (!lastIt) {
            STAGE_B(0, 1, kb2);
            asm volatile("s_waitcnt vmcnt(4)" ::: "memory");
        } else {
            asm volatile("s_waitcnt vmcnt(0)" ::: "memory");
        }
        __builtin_amdgcn_sched_barrier(0);
        PHASE_MID();
        MFMA_QUAD(a1, bq1, 4);
        PHASE_END();

        LD_A4(a0, rA1, 0, su0);
        LD_B4(bq0, rB1, su0);
        if (!lastIt) STAGE_A(0, 0, kb2);
        PHASE_MID();
        MFMA_QUAD(a0, bq0, 0);
        PHASE_END();

        LD_A4(a1, rA1, 0, su1);
        LD_B4(bq1, rB1, su1);
        if (!lastIt) STAGE_A(0, 1, kb2);
        PHASE_MID();
        MFMA_QUAD(a1, bq1, 0);
        PHASE_END();

        LD_A4(a0, rA1, 8192, su0);
        if (!lastIt) STAGE_B(1, 0, kb3);
        PHASE_MID();
        MFMA_QUAD(a0, bq0, 4);
        PHASE_END();

        LD_A4(a1, rA1, 8192, su1);
        if (!lastIt) {
            STAGE_B(1, 1, kb3);
            asm volatile("s_waitcnt vmcnt(4)" ::: "memory");
            __builtin_amdgcn_sched_barrier(0);
        }
        PHASE_MID();
        MFMA_QUAD(a1, bq1, 4);
        PHASE_END();
    }

    int lc[4];
    #pragma unroll
    for (int n = 0; n < 4; ++n)
        lc[n] = labels[colStart + wn * 64 + n * 16 + lr];

    float colAll[4] = {0.f, 0.f, 0.f, 0.f};
    float colPos[4] = {0.f, 0.f, 0.f, 0.f};
    #pragma unroll
    for (int m = 0; m < 8; ++m) {
        #pragma unroll
        for (int e = 0; e < 4; ++e) {
            const int rloc = wm * 128 + m * 16 + q * 4 + e;
            const int gi   = rowStart + rloc;
            const int li   = labels[gi];
            float s_all = 0.f, s_pos = 0.f;
            #pragma unroll
            for (int n = 0; n < 4; ++n) {
                const int cloc = wn * 64 + n * 16 + lr;
                const int gj   = colStart + cloc;
                const float v  = __expf(acc[m][n][e] * invT);
                const bool same = (lc[n] == li);
                s_all += v;
                if (same && gi != gj) s_pos += v;
                if (!isDiag) {
                    colAll[n] += v;
                    if (same) colPos[n] += v;
                }
            }
            #pragma unroll
            for (int off = 1; off < 16; off <<= 1) {
                s_all += __shfl_xor(s_all, off, 64);
                s_pos += __shfl_xor(s_pos, off, 64);
            }
            if (lr == 0) {
                atomicAdd(&sumExp[gi], s_all);
                atomicAdd(&posSum[gi], s_pos);
            }
        }
    }
    if (!isDiag) {
        #pragma unroll
        for (int n = 0; n < 4; ++n) {
            float a = colAll[n], p = colPos[n];
            a += __shfl_xor(a, 16, 64);  a += __shfl_xor(a, 32, 64);
            p += __shfl_xor(p, 16, 64);  p += __shfl_xor(p, 32, 64);
            if (q == 0) {
                const int gj = colStart + wn * 64 + n * 16 + lr;
                atomicAdd(&sumExp[gj], a);
                atomicAdd(&posSum[gj], p);
            }
        }
    }
}

// ---------------------------------------------------------------------------
// Kernel 3: loss_i = log(sumExp_i / posSum_i); out = mean(loss).
// ---------------------------------------------------------------------------
__global__ __launch_bounds__(1024) void finalize(const float* __restrict__ sumExp,
                                                 const float* __restrict__ posSum,
                                                 float* __restrict__ out) {
    const int tid = threadIdx.x;
    float s = 0.f;
    #pragma unroll
    for (int i = tid; i < N; i += 1024)
        s += __logf(sumExp[i] / posSum[i]);
    #pragma unroll
    for (int off = 32; off >= 1; off >>= 1) s += __shfl_xor(s, off, 64);
    __shared__ float red[16];
    if ((tid & 63) == 0) red[tid >> 6] = s;
    __syncthreads();
    if (tid == 0) {
        float t = 0.f;
        #pragma unroll
        for (int i = 0; i < 16; ++i) t += red[i];
        out[0] = t / (float)N;
    }
}

extern "C" void kernel_launch(void* const* d_in, const int* in_sizes, int n_in,
                              void* d_out, int out_size, void* d_ws, size_t ws_size,
                              hipStream_t stream) {
    const float* emb    = (const float*)d_in[0];
    const int*   labels = (const int*)d_in[1];
    float* out = (float*)d_out;

    // ws layout: [sumExp: N floats][posSum: N floats][EN: N*D bf16]
    float*  sumExp = (float*)d_ws;
    float*  posSum = sumExp + N;
    bf16_t* EN     = (bf16_t*)((char*)d_ws + (size_t)2 * N * sizeof(float));

    norm_cast<<<N / 4, 256, 0, stream>>>(emb, EN, sumExp, posSum);

    gemm_fused<<<NBLK, 512, 0, stream>>>(EN, labels, sumExp, posSum);

    finalize<<<1, 1024, 0, stream>>>(sumExp, posSum, out);
}